// Round 8
// baseline (224.039 us; speedup 1.0000x reference)
//
#include <hip/hip_runtime.h>
#include <hip/hip_bf16.h>

#define B_ 2
#define S_ 2048
#define HID 1024
#define NH 16
#define DH 64
#define QKV_N (3*HID)
#define M_ROWS (B_*S_)

typedef __attribute__((ext_vector_type(8))) short short8;
typedef __attribute__((ext_vector_type(4))) short short4v;
typedef __attribute__((ext_vector_type(4))) float floatx4;
typedef unsigned int uint;

__device__ __forceinline__ short8 load8(const __hip_bfloat16* p) {
    return *(const short8*)p;
}

#if __has_builtin(__builtin_amdgcn_exp2f)
#define EXP2F(x) __builtin_amdgcn_exp2f(x)
#else
#define EXP2F(x) exp2f(x)
#endif

// pack two f32 -> packed bf16 pair, round-half-up (1 add each + 1 v_perm)
__device__ __forceinline__ uint pack_bf16_2(float lo, float hi) {
    uint ul = __float_as_uint(lo) + 0x8000u;
    uint uh = __float_as_uint(hi) + 0x8000u;
    return __builtin_amdgcn_perm(uh, ul, 0x07060302);
}
// RTNE variant (for weight/input conversion)
__device__ __forceinline__ uint pack_bf16_2_rtne(float lo, float hi) {
    uint ul = __float_as_uint(lo); ul += 0x7FFFu + ((ul >> 16) & 1u);
    uint uh = __float_as_uint(hi); uh += 0x7FFFu + ((uh >> 16) & 1u);
    return __builtin_amdgcn_perm(uh, ul, 0x07060302);
}

// async global->LDS, 16B per lane; LDS dest = wave-uniform base + lane*16
#define ASYNC16(gptr, lptr) \
    __builtin_amdgcn_global_load_lds((const __attribute__((address_space(1))) void*)(gptr), \
                                     (__attribute__((address_space(3))) void*)(lptr), 16, 0, 0)

// single merged f32->bf16 conversion over x | w_qkv | w_out (outputs contiguous).
__global__ __launch_bounds__(256) void cvt_all(
    const float* __restrict__ x, const float* __restrict__ wq,
    const float* __restrict__ wo, __hip_bfloat16* __restrict__ out)
{
    const int n0 = M_ROWS * HID, n1 = QKV_N * HID;
    int i = (blockIdx.x * 256 + threadIdx.x) * 4;
    const float* src; int off;
    if (i < n0)           { src = x;  off = i; }
    else if (i < n0 + n1) { src = wq; off = i - n0; }
    else                  { src = wo; off = i - n0 - n1; }
    float4 v = *(const float4*)(src + off);
    uint2 r;
    r.x = pack_bf16_2_rtne(v.x, v.y);
    r.y = pack_bf16_2_rtne(v.z, v.w);
    *(uint2*)(out + i) = r;
}

// C = A * B^T, 128x128 tile, BK=64, global_load_lds staging, XOR-swizzled LDS.
// MODE 1: qkv store (bf16) — n<2048 -> C; n>=2048 (V) -> VT permuted
// MODE 2: bias add (f32), store f32 to Cf
#define BK 64
template<int MODE>
__global__ __launch_bounds__(256) void gemm_bt_kernel(
    const __hip_bfloat16* __restrict__ A,
    const __hip_bfloat16* __restrict__ Bw,
    const float* __restrict__ biasf,
    __hip_bfloat16* __restrict__ C,
    float* __restrict__ Cf,
    __hip_bfloat16* __restrict__ VT,
    int Mdim, int Ndim, int Kdim)
{
    __shared__ alignas(16) __hip_bfloat16 As[128 * BK];
    __shared__ alignas(16) __hip_bfloat16 Bs[128 * BK];

    const int tid  = threadIdx.x;
    const int wave = tid >> 6;
    const int lane = tid & 63;
    const int q = lane >> 4;
    const int r = lane & 15;
    const int m_blk = blockIdx.y * 128;
    const int n_blk = blockIdx.x * 128;
    const int wm = (wave >> 1) * 64;
    const int wn = (wave & 1) * 64;

    const int srow = tid >> 3;
    const int cglob = (tid & 7) ^ ((tid >> 3) & 7);
    const __hip_bfloat16* gA = A + (size_t)(m_blk + srow) * Kdim + cglob * 8;
    const __hip_bfloat16* gB = Bw + (size_t)(n_blk + srow) * Kdim + cglob * 8;
    char* ldsA = (char*)As + (size_t)tid * 16;
    char* ldsB = (char*)Bs + (size_t)tid * 16;

    floatx4 acc[4][4];
#pragma unroll
    for (int i = 0; i < 4; i++)
#pragma unroll
        for (int j = 0; j < 4; j++) acc[i][j] = (floatx4){0.f, 0.f, 0.f, 0.f};

    for (int kt = 0; kt < Kdim; kt += BK) {
        __syncthreads();
#pragma unroll
        for (int c = 0; c < 4; c++) {
            ASYNC16(gA + kt + (size_t)(c * 32) * Kdim, ldsA + c * 4096);
            ASYNC16(gB + kt + (size_t)(c * 32) * Kdim, ldsB + c * 4096);
        }
        __builtin_amdgcn_s_waitcnt(0);
        __syncthreads();

#pragma unroll
        for (int kh = 0; kh < 2; kh++) {
            short8 a[4], b[4];
#pragma unroll
            for (int i = 0; i < 4; i++)
                a[i] = *(const short8*)&As[(wm + i * 16 + r) * BK + (((kh * 4 + q) ^ (r & 7)) * 8)];
#pragma unroll
            for (int j = 0; j < 4; j++)
                b[j] = *(const short8*)&Bs[(wn + j * 16 + r) * BK + (((kh * 4 + q) ^ (r & 7)) * 8)];
#pragma unroll
            for (int i = 0; i < 4; i++)
#pragma unroll
                for (int j = 0; j < 4; j++)
                    acc[i][j] = __builtin_amdgcn_mfma_f32_16x16x32_bf16(a[i], b[j], acc[i][j], 0, 0, 0);
        }
    }

#pragma unroll
    for (int i = 0; i < 4; i++) {
#pragma unroll
        for (int j = 0; j < 4; j++) {
#pragma unroll
            for (int reg = 0; reg < 4; reg++) {
                int m = m_blk + wm + i * 16 + q * 4 + reg;
                int n = n_blk + wn + j * 16 + r;
                float v = acc[i][j][reg];
                if (MODE == 2) {
                    Cf[(size_t)m * Ndim + n] = v + biasf[n];
                } else {
                    __hip_bfloat16 hv = __float2bfloat16(v);
                    if (n < 2 * HID) {
                        C[(size_t)m * QKV_N + n] = hv;
                    } else {
                        int dfull = n - 2 * HID;
                        int bidx = m >> 11;
                        int s = m & (S_ - 1);
                        int c = s & 63;
                        int sp = (s & ~63) | ((c & 15) << 2) | ((c >> 4) & 3);
                        VT[((size_t)bidx * HID + dfull) * S_ + sp] = hv;
                    }
                }
            }
        }
    }
}

// Flash attention v7: K-split wave pairs + double-buffered K LDS (prefetch next
// tile during compute) + V B-frags direct global->register (overlap QK/softmax).
// One barrier per iteration, no exposed DMA drain.
#define KT 64
#define PPAD 72
#define SCALE2 0.18033688f   // 0.125 * log2(e)
#define FM2 23.083120f       // 16 * log2(e); exp2(s*SCALE2 - FM2) = exp(s/8 - 16)

__global__ __launch_bounds__(256, 3) void flash_kernel(
    const __hip_bfloat16* __restrict__ qkv,  // [B][S][3072]
    const __hip_bfloat16* __restrict__ VTp,  // [B][HID][S'] (V^T, k-permuted per 64-block)
    __hip_bfloat16* __restrict__ O)          // [B][S][1024]
{
    __shared__ alignas(16) __hip_bfloat16 lds_k[2][2][64 * 64];  // [buf][khid], 32KB
    __shared__ alignas(16) __hip_bfloat16 lds_p[4][32 * PPAD];   // 18KB

    const int tid  = threadIdx.x;
    const int wave = tid >> 6;
    const int lane = tid & 63;
    const int q = lane >> 4;
    const int r = lane & 15;
    const int p     = wave & 1;    // q-half (rows)
    const int khid  = wave >> 1;   // k-half (seq)
    const int bh = blockIdx.x;
    const int b  = bh >> 4;
    const int h  = bh & 15;
    const int s0 = blockIdx.y * 64 + p * 32;

    const __hip_bfloat16* Qbase = qkv + (size_t)b * S_ * QKV_N + h * DH;
    const __hip_bfloat16* Kbase = Qbase + HID;
    const __hip_bfloat16* Vbase = VTp + ((size_t)b * HID + h * DH) * S_;

    // K staging: pair splits tile rows by p; lane -> row sr, slot lane&7,
    // global chunk = slot^(row&7); LDS elem offset = p*2048 + 8*lane (+c*512)
    const int sr = p * 32 + (lane >> 3);
    const int cglob = (lane & 7) ^ ((lane >> 3) & 7);
    const __hip_bfloat16* gK = Kbase + (size_t)(khid * 1024 + sr) * QKV_N + cglob * 8;
    const int ldso = sr * 64 + (lane & 7) * 8;
    const int ktbase = khid * 1024;

    short8 a_q[2][2];
#pragma unroll
    for (int rt = 0; rt < 2; rt++)
#pragma unroll
        for (int kh = 0; kh < 2; kh++)
            a_q[rt][kh] = load8(Qbase + (size_t)(s0 + rt * 16 + r) * QKV_N + kh * 32 + q * 8);

    floatx4 o_acc[2][4];
    floatx4 l_acc[2];
#pragma unroll
    for (int rt = 0; rt < 2; rt++) {
        l_acc[rt] = (floatx4){0.f, 0.f, 0.f, 0.f};
#pragma unroll
        for (int nb = 0; nb < 4; nb++) o_acc[rt][nb] = (floatx4){0.f, 0.f, 0.f, 0.f};
    }

    short8 ones;
#pragma unroll
    for (int i = 0; i < 8; i++) ones[i] = (short)0x3F80;

    __hip_bfloat16* Pw = &lds_p[wave][0];

    // prologue: stage K tile 0 into buf 0; one-time full drain
#pragma unroll
    for (int c = 0; c < 4; c++)
        ASYNC16(gK + (size_t)(c * 8) * QKV_N, &lds_k[0][khid][ldso + c * 512]);
    __builtin_amdgcn_s_waitcnt(0x0F70);  // vmcnt(0)
    __syncthreads();

    for (int it = 0; it < 16; it++) {
        const int cur = it & 1, nxt = cur ^ 1;
        const int ktg = ktbase + it * KT;   // global seq offset of current tile

        // prefetch next K tile (completes during this iteration's compute)
        if (it + 1 < 16) {
#pragma unroll
            for (int c = 0; c < 4; c++)
                ASYNC16(gK + (size_t)((it + 1) * KT + c * 8) * QKV_N, &lds_k[nxt][khid][ldso + c * 512]);
        }
        // V B-frags direct from global (consumed after softmax — overlaps)
        short8 vb[4][2];
#pragma unroll
        for (int nb = 0; nb < 4; nb++)
#pragma unroll
            for (int kh = 0; kh < 2; kh++)
                vb[nb][kh] = load8(Vbase + (size_t)(nb * 16 + r) * S_ + ktg + kh * 32 + q * 8);

        // K frags from current buffer: row = ct*16+r, chunk = kh*4+q
        short8 bk[4][2];
#pragma unroll
        for (int ct = 0; ct < 4; ct++)
#pragma unroll
            for (int kh = 0; kh < 2; kh++)
                bk[ct][kh] = *(const short8*)&lds_k[cur][khid][(ct * 16 + r) * 64 + ((kh * 4 + q) ^ (r & 7)) * 8];

#pragma unroll
        for (int rt = 0; rt < 2; rt++) {
            floatx4 sc[4];
#pragma unroll
            for (int ct = 0; ct < 4; ct++) {
                floatx4 z = (floatx4){0.f, 0.f, 0.f, 0.f};
                z = __builtin_amdgcn_mfma_f32_16x16x32_bf16(a_q[rt][0], bk[ct][0], z, 0, 0, 0);
                z = __builtin_amdgcn_mfma_f32_16x16x32_bf16(a_q[rt][1], bk[ct][1], z, 0, 0, 0);
                sc[ct] = z;
            }
            // P row = rt*16+q*4+reg, score col ct*16+r stored at k~ = 4r+ct
#pragma unroll
            for (int reg = 0; reg < 4; reg++) {
                float e0 = EXP2F(fmaf(sc[0][reg], SCALE2, -FM2));
                float e1 = EXP2F(fmaf(sc[1][reg], SCALE2, -FM2));
                float e2 = EXP2F(fmaf(sc[2][reg], SCALE2, -FM2));
                float e3 = EXP2F(fmaf(sc[3][reg], SCALE2, -FM2));
                uint2 pw;
                pw.x = pack_bf16_2(e0, e1);
                pw.y = pack_bf16_2(e2, e3);
                *(uint2*)&Pw[(rt * 16 + q * 4 + reg) * PPAD + 4 * r] = pw;
            }
        }
        __builtin_amdgcn_s_waitcnt(0xc07f);  // lgkmcnt(0): P visible wave-wide

#pragma unroll
        for (int rt = 0; rt < 2; rt++) {
            short8 pa0 = *(const short8*)&Pw[(rt * 16 + r) * PPAD + q * 8];
            short8 pa1 = *(const short8*)&Pw[(rt * 16 + r) * PPAD + 32 + q * 8];
            l_acc[rt] = __builtin_amdgcn_mfma_f32_16x16x32_bf16(pa0, ones, l_acc[rt], 0, 0, 0);
            l_acc[rt] = __builtin_amdgcn_mfma_f32_16x16x32_bf16(pa1, ones, l_acc[rt], 0, 0, 0);
#pragma unroll
            for (int nb = 0; nb < 4; nb++) {
                o_acc[rt][nb] = __builtin_amdgcn_mfma_f32_16x16x32_bf16(pa0, vb[nb][0], o_acc[rt][nb], 0, 0, 0);
                o_acc[rt][nb] = __builtin_amdgcn_mfma_f32_16x16x32_bf16(pa1, vb[nb][1], o_acc[rt][nb], 0, 0, 0);
            }
        }
        // V loads consumed => their vmcnt retired => older K glds retired too;
        // this drain is ~free, and the barrier publishes buf[nxt] block-wide.
        __builtin_amdgcn_s_waitcnt(0x0F70);  // vmcnt(0)
        __syncthreads();
    }

    // combine k-halves (o,l additive under fixed-max softmax)
    float* of = (float*)&lds_k[0][0][0];   // 16KB of the K buffers, now dead
    float* lf = (float*)&lds_k[1][0][0];
    if (khid == 1) {
#pragma unroll
        for (int rt = 0; rt < 2; rt++) {
#pragma unroll
            for (int nb = 0; nb < 4; nb++)
                *(floatx4*)&of[p * 2048 + (rt * 4 + nb) * 256 + lane * 4] = o_acc[rt][nb];
            *(floatx4*)&lf[p * 512 + rt * 256 + lane * 4] = l_acc[rt];
        }
    }
    __syncthreads();
    if (khid == 0) {
#pragma unroll
        for (int rt = 0; rt < 2; rt++) {
            l_acc[rt] += *(const floatx4*)&lf[p * 512 + rt * 256 + lane * 4];
#pragma unroll
            for (int nb = 0; nb < 4; nb++)
                o_acc[rt][nb] += *(const floatx4*)&of[p * 2048 + (rt * 4 + nb) * 256 + lane * 4];
        }
#pragma unroll
        for (int rt = 0; rt < 2; rt++) {
#pragma unroll
            for (int reg = 0; reg < 4; reg++) {
                float inv = 1.f / l_acc[rt][reg];
                int srow2 = s0 + rt * 16 + q * 4 + reg;
                __hip_bfloat16* Orow = O + ((size_t)b * S_ + srow2) * HID + h * DH;
#pragma unroll
                for (int nb = 0; nb < 4; nb++)
                    Orow[nb * 16 + r] = __float2bfloat16(o_acc[rt][nb][reg] * inv);
            }
        }
    }
}

extern "C" void kernel_launch(void* const* d_in, const int* in_sizes, int n_in,
                              void* d_out, int out_size, void* d_ws, size_t ws_size,
                              hipStream_t stream) {
    const float* x_f     = (const float*)d_in[0];
    const float* w_qkv_f = (const float*)d_in[1];
    const float* w_out_f = (const float*)d_in[2];
    const float* b_out_f = (const float*)d_in[3];
    float* out = (float*)d_out;

    __hip_bfloat16* xb      = (__hip_bfloat16*)d_ws;
    __hip_bfloat16* wqkvb   = xb    + (size_t)M_ROWS * HID;
    __hip_bfloat16* woutb   = wqkvb + (size_t)QKV_N * HID;
    __hip_bfloat16* qkv_ws  = woutb + (size_t)HID * HID;
    __hip_bfloat16* vt_ws   = qkv_ws + (size_t)M_ROWS * QKV_N;
    __hip_bfloat16* attn_ws = vt_ws + (size_t)B_ * HID * S_;

    dim3 blk(256);
    {
        int ntot = M_ROWS * HID + QKV_N * HID + HID * HID;  // 8.4M, /1024 blocks
        cvt_all<<<dim3(ntot / 1024), blk, 0, stream>>>(x_f, w_qkv_f, w_out_f, xb);
    }

    gemm_bt_kernel<1><<<dim3(QKV_N / 128, M_ROWS / 128), blk, 0, stream>>>(
        xb, wqkvb, nullptr, qkv_ws, nullptr, vt_ws, M_ROWS, QKV_N, HID);
    // attention: grid (bh, qtile) — bh fastest for XCD L2 pinning
    flash_kernel<<<dim3(B_ * NH, S_ / 64), dim3(256), 0, stream>>>(qkv_ws, vt_ws, attn_ws);
    gemm_bt_kernel<2><<<dim3(HID / 128, M_ROWS / 128), blk, 0, stream>>>(
        attn_ws, woutb, b_out_f, nullptr, out, nullptr, M_ROWS, HID, HID);
}

// Round 9
// 203.623 us; speedup vs baseline: 1.1003x; 1.1003x over previous
//
#include <hip/hip_runtime.h>
#include <hip/hip_bf16.h>

#define B_ 2
#define S_ 2048
#define HID 1024
#define NH 16
#define DH 64
#define QKV_N (3*HID)
#define M_ROWS (B_*S_)

typedef __attribute__((ext_vector_type(8))) short short8;
typedef __attribute__((ext_vector_type(4))) short short4v;
typedef __attribute__((ext_vector_type(4))) float floatx4;
typedef unsigned int uint;

__device__ __forceinline__ short8 load8(const __hip_bfloat16* p) {
    return *(const short8*)p;
}

#if __has_builtin(__builtin_amdgcn_exp2f)
#define EXP2F(x) __builtin_amdgcn_exp2f(x)
#else
#define EXP2F(x) exp2f(x)
#endif

// pack two f32 -> packed bf16 pair, round-half-up (1 add each + 1 v_perm)
__device__ __forceinline__ uint pack_bf16_2(float lo, float hi) {
    uint ul = __float_as_uint(lo) + 0x8000u;
    uint uh = __float_as_uint(hi) + 0x8000u;
    return __builtin_amdgcn_perm(uh, ul, 0x07060302);
}
// RTNE variant (for weight/input conversion)
__device__ __forceinline__ uint pack_bf16_2_rtne(float lo, float hi) {
    uint ul = __float_as_uint(lo); ul += 0x7FFFu + ((ul >> 16) & 1u);
    uint uh = __float_as_uint(hi); uh += 0x7FFFu + ((uh >> 16) & 1u);
    return __builtin_amdgcn_perm(uh, ul, 0x07060302);
}

// async global->LDS, 16B per lane; LDS dest = wave-uniform base + lane*16
#define ASYNC16(gptr, lptr) \
    __builtin_amdgcn_global_load_lds((const __attribute__((address_space(1))) void*)(gptr), \
                                     (__attribute__((address_space(3))) void*)(lptr), 16, 0, 0)

// single merged f32->bf16 conversion over x | w_qkv | w_out (outputs contiguous).
__global__ __launch_bounds__(256) void cvt_all(
    const float* __restrict__ x, const float* __restrict__ wq,
    const float* __restrict__ wo, __hip_bfloat16* __restrict__ out)
{
    const int n0 = M_ROWS * HID, n1 = QKV_N * HID;
    int i = (blockIdx.x * 256 + threadIdx.x) * 4;
    const float* src; int off;
    if (i < n0)           { src = x;  off = i; }
    else if (i < n0 + n1) { src = wq; off = i - n0; }
    else                  { src = wo; off = i - n0 - n1; }
    float4 v = *(const float4*)(src + off);
    uint2 r;
    r.x = pack_bf16_2_rtne(v.x, v.y);
    r.y = pack_bf16_2_rtne(v.z, v.w);
    *(uint2*)(out + i) = r;
}

// C = A * B^T, 128x128 tile, BK=64, DOUBLE-BUFFERED global_load_lds staging,
// XOR-swizzled LDS (chunk (row,c) at slot c^(row&7)). One barrier per K-tile,
// prefetch overlaps the whole MFMA body.
// MODE 1: qkv store (bf16) — n<2048 -> C; n>=2048 (V) -> VT permuted
// MODE 2: bias add (f32), store f32 to Cf
#define BK 64
template<int MODE>
__global__ __launch_bounds__(256) void gemm_bt_kernel(
    const __hip_bfloat16* __restrict__ A,
    const __hip_bfloat16* __restrict__ Bw,
    const float* __restrict__ biasf,
    __hip_bfloat16* __restrict__ C,
    float* __restrict__ Cf,
    __hip_bfloat16* __restrict__ VT,
    int Mdim, int Ndim, int Kdim)
{
    __shared__ alignas(16) __hip_bfloat16 As[2][128 * BK];  // 2 x 16KB
    __shared__ alignas(16) __hip_bfloat16 Bs[2][128 * BK];

    const int tid  = threadIdx.x;
    const int wave = tid >> 6;
    const int lane = tid & 63;
    const int q = lane >> 4;
    const int r = lane & 15;
    const int m_blk = blockIdx.y * 128;
    const int n_blk = blockIdx.x * 128;
    const int wm = (wave >> 1) * 64;
    const int wn = (wave & 1) * 64;

    const int srow = tid >> 3;
    const int cglob = (tid & 7) ^ ((tid >> 3) & 7);
    const __hip_bfloat16* gA = A + (size_t)(m_blk + srow) * Kdim + cglob * 8;
    const __hip_bfloat16* gB = Bw + (size_t)(n_blk + srow) * Kdim + cglob * 8;
    const int ldso = tid * 8;   // element offset of this thread's 16B chunk

    floatx4 acc[4][4];
#pragma unroll
    for (int i = 0; i < 4; i++)
#pragma unroll
        for (int j = 0; j < 4; j++) acc[i][j] = (floatx4){0.f, 0.f, 0.f, 0.f};

    const int niter = Kdim / BK;
    // prologue: stage tile 0 into buf 0
#pragma unroll
    for (int c = 0; c < 4; c++) {
        ASYNC16(gA + (size_t)(c * 32) * Kdim, &As[0][ldso + c * 2048]);
        ASYNC16(gB + (size_t)(c * 32) * Kdim, &Bs[0][ldso + c * 2048]);
    }
    __builtin_amdgcn_s_waitcnt(0x0F70);  // vmcnt(0)
    __syncthreads();

    for (int it = 0; it < niter; it++) {
        const int cur = it & 1, nxt = cur ^ 1;
        if (it + 1 < niter) {
            const int kt = (it + 1) * BK;
#pragma unroll
            for (int c = 0; c < 4; c++) {
                ASYNC16(gA + kt + (size_t)(c * 32) * Kdim, &As[nxt][ldso + c * 2048]);
                ASYNC16(gB + kt + (size_t)(c * 32) * Kdim, &Bs[nxt][ldso + c * 2048]);
            }
        }
#pragma unroll
        for (int kh = 0; kh < 2; kh++) {
            short8 a[4], b[4];
#pragma unroll
            for (int i = 0; i < 4; i++)
                a[i] = *(const short8*)&As[cur][(wm + i * 16 + r) * BK + (((kh * 4 + q) ^ (r & 7)) * 8)];
#pragma unroll
            for (int j = 0; j < 4; j++)
                b[j] = *(const short8*)&Bs[cur][(wn + j * 16 + r) * BK + (((kh * 4 + q) ^ (r & 7)) * 8)];
#pragma unroll
            for (int i = 0; i < 4; i++)
#pragma unroll
                for (int j = 0; j < 4; j++)
                    acc[i][j] = __builtin_amdgcn_mfma_f32_16x16x32_bf16(a[i], b[j], acc[i][j], 0, 0, 0);
        }
        __builtin_amdgcn_s_waitcnt(0x0F70);  // vmcnt(0): prefetch landed
        __syncthreads();
    }

#pragma unroll
    for (int i = 0; i < 4; i++) {
#pragma unroll
        for (int j = 0; j < 4; j++) {
#pragma unroll
            for (int reg = 0; reg < 4; reg++) {
                int m = m_blk + wm + i * 16 + q * 4 + reg;
                int n = n_blk + wn + j * 16 + r;
                float v = acc[i][j][reg];
                if (MODE == 2) {
                    Cf[(size_t)m * Ndim + n] = v + biasf[n];
                } else {
                    __hip_bfloat16 hv = __float2bfloat16(v);
                    if (n < 2 * HID) {
                        C[(size_t)m * QKV_N + n] = hv;
                    } else {
                        int dfull = n - 2 * HID;
                        int bidx = m >> 11;
                        int s = m & (S_ - 1);
                        int c = s & 63;
                        int sp = (s & ~63) | ((c & 15) << 2) | ((c >> 4) & 3);
                        VT[((size_t)bidx * HID + dfull) * S_ + sp] = hv;
                    }
                }
            }
        }
    }
}

// Flash attention v8: 4 waves share one K/V tile stream (q-tile 128, 32 iters),
// K AND V double-buffered in LDS via global_load_lds; one barrier + one vmcnt
// per iter, prefetch overlaps the whole body. Fast fixed-max softmax (R7).
// LDS 50KB. Grid (bh=32, qt=16) = 512 blocks.
#define KT 64
#define PPAD 72
#define SCALE2 0.18033688f   // 0.125 * log2(e)
#define FM2 23.083120f       // 16 * log2(e); exp2(s*SCALE2 - FM2) = exp(s/8 - 16)

__global__ __launch_bounds__(256, 2) void flash_kernel(
    const __hip_bfloat16* __restrict__ qkv,  // [B][S][3072]
    const __hip_bfloat16* __restrict__ VTp,  // [B][HID][S'] (V^T, k-permuted per 64-block)
    __hip_bfloat16* __restrict__ O)          // [B][S][1024]
{
    __shared__ alignas(16) __hip_bfloat16 lds_k[2][64 * 64];  // 16KB
    __shared__ alignas(16) __hip_bfloat16 lds_v[2][64 * 64];  // 16KB
    __shared__ alignas(16) __hip_bfloat16 lds_p[4][32 * PPAD]; // 18KB

    const int tid  = threadIdx.x;
    const int wave = tid >> 6;
    const int lane = tid & 63;
    const int q = lane >> 4;
    const int r = lane & 15;
    const int bh = blockIdx.x;
    const int b  = bh >> 4;
    const int h  = bh & 15;
    const int s0 = blockIdx.y * 128 + wave * 32;

    const __hip_bfloat16* Qbase = qkv + (size_t)b * S_ * QKV_N + h * DH;
    const __hip_bfloat16* Kbase = Qbase + HID;
    const __hip_bfloat16* Vbase = VTp + ((size_t)b * HID + h * DH) * S_;

    // staging: wave w covers rows w*16..w*16+15 (+8 via c=1) of both tiles.
    // lane -> row = w*16 + (lane>>3), slot = lane&7, global chunk = slot^(row&7)
    const int sr = wave * 16 + (lane >> 3);
    const int cglob = (lane & 7) ^ ((lane >> 3) & 7);
    const __hip_bfloat16* gK = Kbase + (size_t)sr * QKV_N + cglob * 8;
    const __hip_bfloat16* gV = Vbase + (size_t)sr * S_ + cglob * 8;
    const int ldso = sr * 64 + (lane & 7) * 8;

    short8 a_q[2][2];
#pragma unroll
    for (int rt = 0; rt < 2; rt++)
#pragma unroll
        for (int kh = 0; kh < 2; kh++)
            a_q[rt][kh] = load8(Qbase + (size_t)(s0 + rt * 16 + r) * QKV_N + kh * 32 + q * 8);

    floatx4 o_acc[2][4];
    floatx4 l_acc[2];
#pragma unroll
    for (int rt = 0; rt < 2; rt++) {
        l_acc[rt] = (floatx4){0.f, 0.f, 0.f, 0.f};
#pragma unroll
        for (int nb = 0; nb < 4; nb++) o_acc[rt][nb] = (floatx4){0.f, 0.f, 0.f, 0.f};
    }

    short8 ones;
#pragma unroll
    for (int i = 0; i < 8; i++) ones[i] = (short)0x3F80;

    __hip_bfloat16* Pw = &lds_p[wave][0];

    // prologue: stage tile 0 into buf 0
#pragma unroll
    for (int c = 0; c < 2; c++) {
        ASYNC16(gK + (size_t)(c * 8) * QKV_N, &lds_k[0][ldso + c * 512]);
        ASYNC16(gV + (size_t)(c * 8) * S_,    &lds_v[0][ldso + c * 512]);
    }
    __builtin_amdgcn_s_waitcnt(0x0F70);  // vmcnt(0)
    __syncthreads();

    for (int it = 0; it < S_ / KT; it++) {
        const int cur = it & 1, nxt = cur ^ 1;
        // prefetch next tile into buf nxt (window = whole iteration body)
        if (it + 1 < S_ / KT) {
            const int ktn = (it + 1) * KT;
#pragma unroll
            for (int c = 0; c < 2; c++) {
                ASYNC16(gK + (size_t)(ktn + c * 8) * QKV_N, &lds_k[nxt][ldso + c * 512]);
                ASYNC16(gV + (size_t)(c * 8) * S_ + ktn,    &lds_v[nxt][ldso + c * 512]);
            }
        }

        // K frags: row = ct*16+r, chunk = kh*4+q
        short8 bk[4][2];
#pragma unroll
        for (int ct = 0; ct < 4; ct++)
#pragma unroll
            for (int kh = 0; kh < 2; kh++)
                bk[ct][kh] = *(const short8*)&lds_k[cur][(ct * 16 + r) * 64 + ((kh * 4 + q) ^ (r & 7)) * 8];

#pragma unroll
        for (int rt = 0; rt < 2; rt++) {
            floatx4 sc[4];
#pragma unroll
            for (int ct = 0; ct < 4; ct++) {
                floatx4 z = (floatx4){0.f, 0.f, 0.f, 0.f};
                z = __builtin_amdgcn_mfma_f32_16x16x32_bf16(a_q[rt][0], bk[ct][0], z, 0, 0, 0);
                z = __builtin_amdgcn_mfma_f32_16x16x32_bf16(a_q[rt][1], bk[ct][1], z, 0, 0, 0);
                sc[ct] = z;
            }
            // P row = rt*16+q*4+reg, score col ct*16+r stored at k~ = 4r+ct
#pragma unroll
            for (int reg = 0; reg < 4; reg++) {
                float e0 = EXP2F(fmaf(sc[0][reg], SCALE2, -FM2));
                float e1 = EXP2F(fmaf(sc[1][reg], SCALE2, -FM2));
                float e2 = EXP2F(fmaf(sc[2][reg], SCALE2, -FM2));
                float e3 = EXP2F(fmaf(sc[3][reg], SCALE2, -FM2));
                uint2 pw;
                pw.x = pack_bf16_2(e0, e1);
                pw.y = pack_bf16_2(e2, e3);
                *(uint2*)&Pw[(rt * 16 + q * 4 + reg) * PPAD + 4 * r] = pw;
            }
        }
        __builtin_amdgcn_s_waitcnt(0xc07f);  // lgkmcnt(0): P visible wave-wide

        // V frags: row d = nb*16+r, chunk = kh*4+q
        short8 vb[4][2];
#pragma unroll
        for (int nb = 0; nb < 4; nb++)
#pragma unroll
            for (int kh = 0; kh < 2; kh++)
                vb[nb][kh] = *(const short8*)&lds_v[cur][(nb * 16 + r) * 64 + ((kh * 4 + q) ^ (r & 7)) * 8];

#pragma unroll
        for (int rt = 0; rt < 2; rt++) {
            short8 pa0 = *(const short8*)&Pw[(rt * 16 + r) * PPAD + q * 8];
            short8 pa1 = *(const short8*)&Pw[(rt * 16 + r) * PPAD + 32 + q * 8];
            l_acc[rt] = __builtin_amdgcn_mfma_f32_16x16x32_bf16(pa0, ones, l_acc[rt], 0, 0, 0);
            l_acc[rt] = __builtin_amdgcn_mfma_f32_16x16x32_bf16(pa1, ones, l_acc[rt], 0, 0, 0);
#pragma unroll
            for (int nb = 0; nb < 4; nb++) {
                o_acc[rt][nb] = __builtin_amdgcn_mfma_f32_16x16x32_bf16(pa0, vb[nb][0], o_acc[rt][nb], 0, 0, 0);
                o_acc[rt][nb] = __builtin_amdgcn_mfma_f32_16x16x32_bf16(pa1, vb[nb][1], o_acc[rt][nb], 0, 0, 0);
            }
        }
        __builtin_amdgcn_s_waitcnt(0x0F70);  // vmcnt(0): prefetch landed
        __syncthreads();                     // all waves done reading cur; nxt published
    }

    // normalize + store: O[b][s][h*64+d]
#pragma unroll
    for (int rt = 0; rt < 2; rt++) {
#pragma unroll
        for (int reg = 0; reg < 4; reg++) {
            float inv = 1.f / l_acc[rt][reg];
            int srow2 = s0 + rt * 16 + q * 4 + reg;
            __hip_bfloat16* Orow = O + ((size_t)b * S_ + srow2) * HID + h * DH;
#pragma unroll
            for (int nb = 0; nb < 4; nb++)
                Orow[nb * 16 + r] = __float2bfloat16(o_acc[rt][nb][reg] * inv);
        }
    }
}

extern "C" void kernel_launch(void* const* d_in, const int* in_sizes, int n_in,
                              void* d_out, int out_size, void* d_ws, size_t ws_size,
                              hipStream_t stream) {
    const float* x_f     = (const float*)d_in[0];
    const float* w_qkv_f = (const float*)d_in[1];
    const float* w_out_f = (const float*)d_in[2];
    const float* b_out_f = (const float*)d_in[3];
    float* out = (float*)d_out;

    __hip_bfloat16* xb      = (__hip_bfloat16*)d_ws;
    __hip_bfloat16* wqkvb   = xb    + (size_t)M_ROWS * HID;
    __hip_bfloat16* woutb   = wqkvb + (size_t)QKV_N * HID;
    __hip_bfloat16* qkv_ws  = woutb + (size_t)HID * HID;
    __hip_bfloat16* vt_ws   = qkv_ws + (size_t)M_ROWS * QKV_N;
    __hip_bfloat16* attn_ws = vt_ws + (size_t)B_ * HID * S_;

    dim3 blk(256);
    {
        int ntot = M_ROWS * HID + QKV_N * HID + HID * HID;  // 8.4M, /1024 blocks
        cvt_all<<<dim3(ntot / 1024), blk, 0, stream>>>(x_f, w_qkv_f, w_out_f, xb);
    }

    gemm_bt_kernel<1><<<dim3(QKV_N / 128, M_ROWS / 128), blk, 0, stream>>>(
        xb, wqkvb, nullptr, qkv_ws, nullptr, vt_ws, M_ROWS, QKV_N, HID);
    // attention: grid (bh, qtile) — bh fastest for XCD L2 pinning
    flash_kernel<<<dim3(B_ * NH, S_ / 128), dim3(256), 0, stream>>>(qkv_ws, vt_ws, attn_ws);
    gemm_bt_kernel<2><<<dim3(HID / 128, M_ROWS / 128), blk, 0, stream>>>(
        attn_ws, woutb, b_out_f, nullptr, out, nullptr, M_ROWS, HID, HID);
}

// Round 10
// 193.276 us; speedup vs baseline: 1.1592x; 1.0535x over previous
//
#include <hip/hip_runtime.h>
#include <hip/hip_bf16.h>

#define B_ 2
#define S_ 2048
#define HID 1024
#define NH 16
#define DH 64
#define QKV_N (3*HID)
#define M_ROWS (B_*S_)

typedef __attribute__((ext_vector_type(8))) short short8;
typedef __attribute__((ext_vector_type(4))) short short4v;
typedef __attribute__((ext_vector_type(4))) float floatx4;
typedef unsigned int uint;

__device__ __forceinline__ short8 load8(const __hip_bfloat16* p) {
    return *(const short8*)p;
}

#if __has_builtin(__builtin_amdgcn_exp2f)
#define EXP2F(x) __builtin_amdgcn_exp2f(x)
#else
#define EXP2F(x) exp2f(x)
#endif

__device__ __forceinline__ uint pack_bf16_2(float lo, float hi) {
    uint ul = __float_as_uint(lo) + 0x8000u;
    uint uh = __float_as_uint(hi) + 0x8000u;
    return __builtin_amdgcn_perm(uh, ul, 0x07060302);
}
__device__ __forceinline__ uint pack_bf16_2_rtne(float lo, float hi) {
    uint ul = __float_as_uint(lo); ul += 0x7FFFu + ((ul >> 16) & 1u);
    uint uh = __float_as_uint(hi); uh += 0x7FFFu + ((uh >> 16) & 1u);
    return __builtin_amdgcn_perm(uh, ul, 0x07060302);
}

#define ASYNC16(gptr, lptr) \
    __builtin_amdgcn_global_load_lds((const __attribute__((address_space(1))) void*)(gptr), \
                                     (__attribute__((address_space(3))) void*)(lptr), 16, 0, 0)
#define RAW_BARRIER() asm volatile("s_barrier" ::: "memory")

// merged f32->bf16 conversion over x | w_qkv | w_out (outputs contiguous)
__global__ __launch_bounds__(256) void cvt_all(
    const float* __restrict__ x, const float* __restrict__ wq,
    const float* __restrict__ wo, __hip_bfloat16* __restrict__ out)
{
    const int n0 = M_ROWS * HID, n1 = QKV_N * HID;
    int i = (blockIdx.x * 256 + threadIdx.x) * 4;
    const float* src; int off;
    if (i < n0)           { src = x;  off = i; }
    else if (i < n0 + n1) { src = wq; off = i - n0; }
    else                  { src = wo; off = i - n0 - n1; }
    float4 v = *(const float4*)(src + off);
    uint2 r;
    r.x = pack_bf16_2_rtne(v.x, v.y);
    r.y = pack_bf16_2_rtne(v.z, v.w);
    *(uint2*)(out + i) = r;
}

// C = A * B^T, K=1024. TMB x 128 tile, BK=32, 3-stage circular LDS pipeline:
// per iter: s_waitcnt vmcnt(G) (only the buffer being read) + RAW s_barrier
// (no compiler drain) + prefetch it+2 + compute. Prefetch stays in flight
// across barriers (AITER/s02 pattern) — never vmcnt(0) except last iter.
// BK=32 rows are 64B -> LDS naturally conflict-free, no swizzle.
// MODE 1: qkv store (bf16) — n<2048 -> C; n>=2048 (V) -> VT permuted
// MODE 2: bias add (f32), store f32 to Cf
#define BK 32
#define NITER 32   // K=1024 / 32
template<int MODE, int TMB>
__global__ __launch_bounds__(256, (TMB == 128) ? 3 : 4) void gemm_bt_kernel(
    const __hip_bfloat16* __restrict__ A,
    const __hip_bfloat16* __restrict__ Bw,
    const float* __restrict__ biasf,
    __hip_bfloat16* __restrict__ C,
    float* __restrict__ Cf,
    __hip_bfloat16* __restrict__ VT,
    int Mdim, int Ndim, int Kdim)
{
    constexpr int NI = TMB / 32;         // m-tiles per wave (4 or 2)
    constexpr int CA = TMB / 64;         // A-chunks per thread (2 or 1)
    constexpr int WAITG = 0x0F70 | (CA + 2);   // vmcnt(glds per wave per buffer)
    __shared__ alignas(16) __hip_bfloat16 As[3][TMB * BK];
    __shared__ alignas(16) __hip_bfloat16 Bs[3][128 * BK];

    const int tid  = threadIdx.x;
    const int wave = tid >> 6;
    const int lane = tid & 63;
    const int q = lane >> 4;
    const int r = lane & 15;
    const int m_blk = blockIdx.y * TMB;
    const int n_blk = blockIdx.x * 128;
    const int wm = (wave >> 1) * (TMB / 2);
    const int wn = (wave & 1) * 64;

    const __hip_bfloat16* Abase = A + (size_t)m_blk * Kdim;
    const __hip_bfloat16* Bbase = Bw + (size_t)n_blk * Kdim;

    floatx4 acc[NI][4];
#pragma unroll
    for (int i = 0; i < NI; i++)
#pragma unroll
        for (int j = 0; j < 4; j++) acc[i][j] = (floatx4){0.f, 0.f, 0.f, 0.f};

    // chunk ch -> row = ch>>2, k-slot = ch&3 (16B); LDS dest = ch*16B (lane-contig)
    auto stage = [&](int bf, int kt) {
#pragma unroll
        for (int c = 0; c < CA; c++) {
            int ch = tid + c * 256;
            ASYNC16(Abase + (size_t)(ch >> 2) * Kdim + kt + (ch & 3) * 8, &As[bf][ch * 8]);
        }
#pragma unroll
        for (int c = 0; c < 2; c++) {
            int ch = tid + c * 256;
            ASYNC16(Bbase + (size_t)(ch >> 2) * Kdim + kt + (ch & 3) * 8, &Bs[bf][ch * 8]);
        }
    };
    auto compute = [&](int bf) {
        short8 a[NI], b[4];
#pragma unroll
        for (int i = 0; i < NI; i++) a[i] = *(const short8*)&As[bf][(wm + i * 16 + r) * BK + q * 8];
#pragma unroll
        for (int j = 0; j < 4; j++) b[j] = *(const short8*)&Bs[bf][(wn + j * 16 + r) * BK + q * 8];
#pragma unroll
        for (int i = 0; i < NI; i++)
#pragma unroll
            for (int j = 0; j < 4; j++)
                acc[i][j] = __builtin_amdgcn_mfma_f32_16x16x32_bf16(a[i], b[j], acc[i][j], 0, 0, 0);
    };

    stage(0, 0);
    stage(1, BK);
    for (int it = 0; it < NITER - 2; it++) {
        __builtin_amdgcn_s_waitcnt(WAITG);   // buffer it staged (own wave)
        RAW_BARRIER();                        // staged block-wide; prev reads done
        stage((it + 2) % 3, (it + 2) * BK);   // prefetch depth 2
        compute(it % 3);
    }
    __builtin_amdgcn_s_waitcnt(WAITG);
    RAW_BARRIER();
    compute((NITER - 2) % 3);
    __builtin_amdgcn_s_waitcnt(0x0F70);       // vmcnt(0): last buffer
    RAW_BARRIER();
    compute((NITER - 1) % 3);

    // epilogue: C/D layout col = lane&15, row = (lane>>4)*4 + reg
#pragma unroll
    for (int i = 0; i < NI; i++) {
#pragma unroll
        for (int j = 0; j < 4; j++) {
#pragma unroll
            for (int reg = 0; reg < 4; reg++) {
                int m = m_blk + wm + i * 16 + q * 4 + reg;
                int n = n_blk + wn + j * 16 + r;
                float v = acc[i][j][reg];
                if (MODE == 2) {
                    Cf[(size_t)m * Ndim + n] = v + biasf[n];
                } else {
                    __hip_bfloat16 hv = __float2bfloat16(v);
                    if (n < 2 * HID) {
                        C[(size_t)m * QKV_N + n] = hv;
                    } else {
                        int dfull = n - 2 * HID;
                        int bidx = m >> 11;
                        int s = m & (S_ - 1);
                        int c = s & 63;
                        int sp = (s & ~63) | ((c & 15) << 2) | ((c >> 4) & 3);
                        VT[((size_t)bidx * HID + dfull) * S_ + sp] = hv;
                    }
                }
            }
        }
    }
}

// Flash attention v9: v8 structure + 3-stage K/V pipeline with raw barriers
// and vmcnt(4) (never drains except last iter). Q drained once in prologue.
#define KT 64
#define PPAD 72
#define SCALE2 0.18033688f   // 0.125 * log2(e)
#define FM2 23.083120f       // 16 * log2(e)

__global__ __launch_bounds__(256, 2) void flash_kernel(
    const __hip_bfloat16* __restrict__ qkv,  // [B][S][3072]
    const __hip_bfloat16* __restrict__ VTp,  // [B][HID][S'] (V^T, k-permuted per 64-block)
    __hip_bfloat16* __restrict__ O)          // [B][S][1024]
{
    __shared__ alignas(16) __hip_bfloat16 lds_k[3][64 * 64];   // 24KB
    __shared__ alignas(16) __hip_bfloat16 lds_v[3][64 * 64];   // 24KB
    __shared__ alignas(16) __hip_bfloat16 lds_p[4][32 * PPAD]; // 18KB

    const int tid  = threadIdx.x;
    const int wave = tid >> 6;
    const int lane = tid & 63;
    const int q = lane >> 4;
    const int r = lane & 15;
    const int bh = blockIdx.x;
    const int b  = bh >> 4;
    const int h  = bh & 15;
    const int s0 = blockIdx.y * 128 + wave * 32;

    const __hip_bfloat16* Qbase = qkv + (size_t)b * S_ * QKV_N + h * DH;
    const __hip_bfloat16* Kbase = Qbase + HID;
    const __hip_bfloat16* Vbase = VTp + ((size_t)b * HID + h * DH) * S_;

    // staging: lane -> tile row sr (+8 via c), slot lane&7, global chunk slot^(row&7)
    const int sr = wave * 16 + (lane >> 3);
    const int cglob = (lane & 7) ^ ((lane >> 3) & 7);
    const __hip_bfloat16* gK = Kbase + (size_t)sr * QKV_N + cglob * 8;
    const __hip_bfloat16* gV = Vbase + (size_t)sr * S_ + cglob * 8;
    const int ldso = sr * 64 + (lane & 7) * 8;

    floatx4 o_acc[2][4];
    floatx4 l_acc[2];
#pragma unroll
    for (int rt = 0; rt < 2; rt++) {
        l_acc[rt] = (floatx4){0.f, 0.f, 0.f, 0.f};
#pragma unroll
        for (int nb = 0; nb < 4; nb++) o_acc[rt][nb] = (floatx4){0.f, 0.f, 0.f, 0.f};
    }

    short8 ones;
#pragma unroll
    for (int i = 0; i < 8; i++) ones[i] = (short)0x3F80;

    __hip_bfloat16* Pw = &lds_p[wave][0];

    auto stage = [&](int bf, int kt) {
#pragma unroll
        for (int c = 0; c < 2; c++) {
            ASYNC16(gK + (size_t)(kt + c * 8) * QKV_N, &lds_k[bf][ldso + c * 512]);
            ASYNC16(gV + (size_t)(c * 8) * S_ + kt,    &lds_v[bf][ldso + c * 512]);
        }
    };

    short8 a_q[2][2];
    auto compute = [&](int bf) {
        short8 bk[4][2];
#pragma unroll
        for (int ct = 0; ct < 4; ct++)
#pragma unroll
            for (int kh = 0; kh < 2; kh++)
                bk[ct][kh] = *(const short8*)&lds_k[bf][(ct * 16 + r) * 64 + ((kh * 4 + q) ^ (r & 7)) * 8];
#pragma unroll
        for (int rt = 0; rt < 2; rt++) {
            floatx4 sc[4];
#pragma unroll
            for (int ct = 0; ct < 4; ct++) {
                floatx4 z = (floatx4){0.f, 0.f, 0.f, 0.f};
                z = __builtin_amdgcn_mfma_f32_16x16x32_bf16(a_q[rt][0], bk[ct][0], z, 0, 0, 0);
                z = __builtin_amdgcn_mfma_f32_16x16x32_bf16(a_q[rt][1], bk[ct][1], z, 0, 0, 0);
                sc[ct] = z;
            }
#pragma unroll
            for (int reg = 0; reg < 4; reg++) {
                float e0 = EXP2F(fmaf(sc[0][reg], SCALE2, -FM2));
                float e1 = EXP2F(fmaf(sc[1][reg], SCALE2, -FM2));
                float e2 = EXP2F(fmaf(sc[2][reg], SCALE2, -FM2));
                float e3 = EXP2F(fmaf(sc[3][reg], SCALE2, -FM2));
                uint2 pw;
                pw.x = pack_bf16_2(e0, e1);
                pw.y = pack_bf16_2(e2, e3);
                *(uint2*)&Pw[(rt * 16 + q * 4 + reg) * PPAD + 4 * r] = pw;
            }
        }
        __builtin_amdgcn_s_waitcnt(0xc07f);  // lgkmcnt(0): P visible wave-wide

        short8 vb[4][2];
#pragma unroll
        for (int nb = 0; nb < 4; nb++)
#pragma unroll
            for (int kh = 0; kh < 2; kh++)
                vb[nb][kh] = *(const short8*)&lds_v[bf][(nb * 16 + r) * 64 + ((kh * 4 + q) ^ (r & 7)) * 8];
#pragma unroll
        for (int rt = 0; rt < 2; rt++) {
            short8 pa0 = *(const short8*)&Pw[(rt * 16 + r) * PPAD + q * 8];
            short8 pa1 = *(const short8*)&Pw[(rt * 16 + r) * PPAD + 32 + q * 8];
            l_acc[rt] = __builtin_amdgcn_mfma_f32_16x16x32_bf16(pa0, ones, l_acc[rt], 0, 0, 0);
            l_acc[rt] = __builtin_amdgcn_mfma_f32_16x16x32_bf16(pa1, ones, l_acc[rt], 0, 0, 0);
#pragma unroll
            for (int nb = 0; nb < 4; nb++) {
                o_acc[rt][nb] = __builtin_amdgcn_mfma_f32_16x16x32_bf16(pa0, vb[nb][0], o_acc[rt][nb], 0, 0, 0);
                o_acc[rt][nb] = __builtin_amdgcn_mfma_f32_16x16x32_bf16(pa1, vb[nb][1], o_acc[rt][nb], 0, 0, 0);
            }
        }
    };

    // prologue: buf0 + Q, full drain once, then buf1 in flight
    stage(0, 0);
#pragma unroll
    for (int rt = 0; rt < 2; rt++)
#pragma unroll
        for (int kh = 0; kh < 2; kh++)
            a_q[rt][kh] = load8(Qbase + (size_t)(s0 + rt * 16 + r) * QKV_N + kh * 32 + q * 8);
    __builtin_amdgcn_s_waitcnt(0x0F70);  // vmcnt(0): buf0 + Q done
    stage(1, KT);

    for (int it = 0; it < 30; it++) {
        __builtin_amdgcn_s_waitcnt(0x0F74);  // vmcnt(4): buffer it staged (own wave)
        RAW_BARRIER();
        stage((it + 2) % 3, (it + 2) * KT);
        compute(it % 3);
    }
    __builtin_amdgcn_s_waitcnt(0x0F74);
    RAW_BARRIER();
    compute(0);                              // it=30
    __builtin_amdgcn_s_waitcnt(0x0F70);
    RAW_BARRIER();
    compute(1);                              // it=31

    // normalize + store
#pragma unroll
    for (int rt = 0; rt < 2; rt++) {
#pragma unroll
        for (int reg = 0; reg < 4; reg++) {
            float inv = 1.f / l_acc[rt][reg];
            int srow2 = s0 + rt * 16 + q * 4 + reg;
            __hip_bfloat16* Orow = O + ((size_t)b * S_ + srow2) * HID + h * DH;
#pragma unroll
            for (int nb = 0; nb < 4; nb++)
                Orow[nb * 16 + r] = __float2bfloat16(o_acc[rt][nb][reg] * inv);
        }
    }
}

extern "C" void kernel_launch(void* const* d_in, const int* in_sizes, int n_in,
                              void* d_out, int out_size, void* d_ws, size_t ws_size,
                              hipStream_t stream) {
    const float* x_f     = (const float*)d_in[0];
    const float* w_qkv_f = (const float*)d_in[1];
    const float* w_out_f = (const float*)d_in[2];
    const float* b_out_f = (const float*)d_in[3];
    float* out = (float*)d_out;

    __hip_bfloat16* xb      = (__hip_bfloat16*)d_ws;
    __hip_bfloat16* wqkvb   = xb    + (size_t)M_ROWS * HID;
    __hip_bfloat16* woutb   = wqkvb + (size_t)QKV_N * HID;
    __hip_bfloat16* qkv_ws  = woutb + (size_t)HID * HID;
    __hip_bfloat16* vt_ws   = qkv_ws + (size_t)M_ROWS * QKV_N;
    __hip_bfloat16* attn_ws = vt_ws + (size_t)B_ * HID * S_;

    dim3 blk(256);
    {
        int ntot = M_ROWS * HID + QKV_N * HID + HID * HID;
        cvt_all<<<dim3(ntot / 1024), blk, 0, stream>>>(x_f, w_qkv_f, w_out_f, xb);
    }

    gemm_bt_kernel<1, 128><<<dim3(QKV_N / 128, M_ROWS / 128), blk, 0, stream>>>(
        xb, wqkvb, nullptr, qkv_ws, nullptr, vt_ws, M_ROWS, QKV_N, HID);
    flash_kernel<<<dim3(B_ * NH, S_ / 128), dim3(256), 0, stream>>>(qkv_ws, vt_ws, attn_ws);
    gemm_bt_kernel<2, 64><<<dim3(HID / 128, M_ROWS / 64), blk, 0, stream>>>(
        attn_ws, woutb, b_out_f, nullptr, out, nullptr, M_ROWS, HID, HID);
}

// Round 12
// 186.894 us; speedup vs baseline: 1.1987x; 1.0341x over previous
//
#include <hip/hip_runtime.h>
#include <hip/hip_bf16.h>

#define B_ 2
#define S_ 2048
#define HID 1024
#define NH 16
#define DH 64
#define QKV_N (3*HID)
#define M_ROWS (B_*S_)

typedef __attribute__((ext_vector_type(8))) short short8;
typedef __attribute__((ext_vector_type(4))) short short4v;
typedef __attribute__((ext_vector_type(4))) float floatx4;
typedef unsigned int uint;

__device__ __forceinline__ short8 load8(const __hip_bfloat16* p) {
    return *(const short8*)p;
}

#if __has_builtin(__builtin_amdgcn_exp2f)
#define EXP2F(x) __builtin_amdgcn_exp2f(x)
#else
#define EXP2F(x) exp2f(x)
#endif

__device__ __forceinline__ uint pack_bf16_2(float lo, float hi) {
    uint ul = __float_as_uint(lo) + 0x8000u;
    uint uh = __float_as_uint(hi) + 0x8000u;
    return __builtin_amdgcn_perm(uh, ul, 0x07060302);
}
__device__ __forceinline__ uint pack_bf16_2_rtne(float lo, float hi) {
    uint ul = __float_as_uint(lo); ul += 0x7FFFu + ((ul >> 16) & 1u);
    uint uh = __float_as_uint(hi); uh += 0x7FFFu + ((uh >> 16) & 1u);
    return __builtin_amdgcn_perm(uh, ul, 0x07060302);
}

#define ASYNC16(gptr, lptr) \
    __builtin_amdgcn_global_load_lds((const __attribute__((address_space(1))) void*)(gptr), \
                                     (__attribute__((address_space(3))) void*)(lptr), 16, 0, 0)
#define RAW_BARRIER() asm volatile("s_barrier" ::: "memory")

// merged f32->bf16 conversion over x | w_qkv | w_out (outputs contiguous)
__global__ __launch_bounds__(256) void cvt_all(
    const float* __restrict__ x, const float* __restrict__ wq,
    const float* __restrict__ wo, __hip_bfloat16* __restrict__ out)
{
    const int n0 = M_ROWS * HID, n1 = QKV_N * HID;
    int i = (blockIdx.x * 256 + threadIdx.x) * 4;
    const float* src; int off;
    if (i < n0)           { src = x;  off = i; }
    else if (i < n0 + n1) { src = wq; off = i - n0; }
    else                  { src = wo; off = i - n0 - n1; }
    float4 v = *(const float4*)(src + off);
    uint2 r;
    r.x = pack_bf16_2_rtne(v.x, v.y);
    r.y = pack_bf16_2_rtne(v.z, v.w);
    *(uint2*)(out + i) = r;
}

// C = A * B^T, K=1024. TMB x 128 tile, BK=32, 3-stage pipeline (raw s_barrier +
// vmcnt(G), prefetch depth 2 — never drains). SWAPPED MFMA operands: per lane
// the 4 acc regs span 4 consecutive n -> vectorized stores.
// MODE 1: qkv (bf16): n<2048 -> C b64 stores; n>=2048 (V) -> VT per-32-permuted
//         (sp = (s&~31) | 2*(s&15) | ((s>>4)&1)), scalar stores.
// MODE 2: bias add, dwordx4 f32 stores.
#define BK 32
#define NITER 32
template<int MODE, int TMB>
__global__ __launch_bounds__(256, (TMB == 128) ? 3 : 4) void gemm_bt_kernel(
    const __hip_bfloat16* __restrict__ A,
    const __hip_bfloat16* __restrict__ Bw,
    const float* __restrict__ biasf,
    __hip_bfloat16* __restrict__ C,
    float* __restrict__ Cf,
    __hip_bfloat16* __restrict__ VT,
    int Mdim, int Ndim, int Kdim)
{
    constexpr int NI = TMB / 32;
    constexpr int CA = TMB / 64;
    constexpr int WAITG = 0x0F70 | (CA + 2);
    __shared__ alignas(16) __hip_bfloat16 As[3][TMB * BK];
    __shared__ alignas(16) __hip_bfloat16 Bs[3][128 * BK];

    const int tid  = threadIdx.x;
    const int wave = tid >> 6;
    const int lane = tid & 63;
    const int q = lane >> 4;
    const int r = lane & 15;
    const int m_blk = blockIdx.y * TMB;
    const int n_blk = blockIdx.x * 128;
    const int wm = (wave >> 1) * (TMB / 2);
    const int wn = (wave & 1) * 64;

    const __hip_bfloat16* Abase = A + (size_t)m_blk * Kdim;
    const __hip_bfloat16* Bbase = Bw + (size_t)n_blk * Kdim;

    floatx4 acc[NI][4];
#pragma unroll
    for (int i = 0; i < NI; i++)
#pragma unroll
        for (int j = 0; j < 4; j++) acc[i][j] = (floatx4){0.f, 0.f, 0.f, 0.f};

    auto stage = [&](int bf, int kt) {
#pragma unroll
        for (int c = 0; c < CA; c++) {
            int ch = tid + c * 256;
            ASYNC16(Abase + (size_t)(ch >> 2) * Kdim + kt + (ch & 3) * 8, &As[bf][ch * 8]);
        }
#pragma unroll
        for (int c = 0; c < 2; c++) {
            int ch = tid + c * 256;
            ASYNC16(Bbase + (size_t)(ch >> 2) * Kdim + kt + (ch & 3) * 8, &Bs[bf][ch * 8]);
        }
    };
    auto compute = [&](int bf) {
        short8 a[NI], b[4];
#pragma unroll
        for (int i = 0; i < NI; i++) a[i] = *(const short8*)&As[bf][(wm + i * 16 + r) * BK + q * 8];
#pragma unroll
        for (int j = 0; j < 4; j++) b[j] = *(const short8*)&Bs[bf][(wn + j * 16 + r) * BK + q * 8];
#pragma unroll
        for (int i = 0; i < NI; i++)
#pragma unroll
            for (int j = 0; j < 4; j++)   // SWAPPED: first operand = B -> acc[m=..+r][n=..+q*4+reg]
                acc[i][j] = __builtin_amdgcn_mfma_f32_16x16x32_bf16(b[j], a[i], acc[i][j], 0, 0, 0);
    };

    stage(0, 0);
    stage(1, BK);
    for (int it = 0; it < NITER - 2; it++) {
        __builtin_amdgcn_s_waitcnt(WAITG);
        RAW_BARRIER();
        stage((it + 2) % 3, (it + 2) * BK);
        compute(it % 3);
    }
    __builtin_amdgcn_s_waitcnt(WAITG);
    RAW_BARRIER();
    compute((NITER - 2) % 3);
    __builtin_amdgcn_s_waitcnt(0x0F70);
    RAW_BARRIER();
    compute((NITER - 1) % 3);

    // epilogue (swapped layout): m = m_blk+wm+i*16+r, n = n_blk+wn+j*16+q*4+reg
#pragma unroll
    for (int i = 0; i < NI; i++) {
        const int m = m_blk + wm + i * 16 + r;
#pragma unroll
        for (int j = 0; j < 4; j++) {
            const int n0 = n_blk + wn + j * 16 + q * 4;
            if (MODE == 2) {
                float4 bv = *(const float4*)&biasf[n0];
                float4 ov;
                ov.x = acc[i][j][0] + bv.x;
                ov.y = acc[i][j][1] + bv.y;
                ov.z = acc[i][j][2] + bv.z;
                ov.w = acc[i][j][3] + bv.w;
                *(float4*)&Cf[(size_t)m * Ndim + n0] = ov;
            } else if (n_blk < 2 * HID) {
                uint2 pk;
                pk.x = pack_bf16_2_rtne(acc[i][j][0], acc[i][j][1]);
                pk.y = pack_bf16_2_rtne(acc[i][j][2], acc[i][j][3]);
                *(uint2*)&C[(size_t)m * QKV_N + n0] = pk;
            } else {
                // V: per-32 permuted transpose store (scalar)
                int bidx = m >> 11;
                int srow = m & (S_ - 1);
                int c = srow & 31;
                int sp = (srow & ~31) | ((c & 15) << 1) | ((c >> 4) & 1);
#pragma unroll
                for (int reg = 0; reg < 4; reg++) {
                    int dfull = n0 + reg - 2 * HID;
                    VT[((size_t)bidx * HID + dfull) * S_ + sp] =
                        __float2bfloat16(acc[i][j][reg]);
                }
            }
        }
    }
}

// Flash attention v10: 512-thr blocks = 4 q-groups (32 rows) x 2 k-halves.
// KT=32 tiles (4KB), 3-stage glds pipeline (vmcnt(2) + raw barrier, depth-2
// prefetch). V^T per-32-permuted; V tile [64d][32s'] with dual-XOR swizzle
// f(row)=(row+(row>>2))&3 (<=2-way on store+b128 read). P [32][PPAD=40].
// LDS 68KB -> 2 blocks/CU = 16 waves/CU. o,l additive across k-halves
// (fixed-max softmax); combined in-block via LDS at the end.
#define KT 32
#define PPAD 40
#define SCALE2 0.18033688f   // 0.125 * log2(e)
#define FM2 23.083120f       // 16 * log2(e)

__global__ __launch_bounds__(512, 4) void flash_kernel(
    const __hip_bfloat16* __restrict__ qkv,  // [B][S][3072]
    const __hip_bfloat16* __restrict__ VTp,  // [B][HID][S'] per-32 permuted
    __hip_bfloat16* __restrict__ O)          // [B][S][1024]
{
    __shared__ alignas(16) char smem[69632];
    __hip_bfloat16* lds_k = (__hip_bfloat16*)smem;            // [3][2][2048] 24KB
    __hip_bfloat16* lds_v = (__hip_bfloat16*)(smem + 24576);  // [3][2][2048] 24KB
    __hip_bfloat16* lds_p = (__hip_bfloat16*)(smem + 49152);  // [8][1280]    20KB

    const int tid  = threadIdx.x;
    const int wave = tid >> 6;
    const int lane = tid & 63;
    const int q = lane >> 4;
    const int r = lane & 15;
    const int ww   = wave & 3;    // q-group
    const int khid = wave >> 2;   // k-half
    const int bh = blockIdx.x;
    const int b  = bh >> 4;
    const int h  = bh & 15;
    const int s0 = blockIdx.y * 128 + ww * 32;

    const __hip_bfloat16* Qbase = qkv + (size_t)b * S_ * QKV_N + h * DH;
    const __hip_bfloat16* Kbase = Qbase + HID;
    const __hip_bfloat16* Vbase = VTp + ((size_t)b * HID + h * DH) * S_;

    // K staging: lane -> row sr = ww*8 + (lane>>3), slot lane&7, chunk slot^(sr&7)
    const int sr = ww * 8 + (lane >> 3);
    const int kcg = (lane & 7) ^ ((lane >> 3) & 7);
    const __hip_bfloat16* gK = Kbase + (size_t)(khid * 1024 + sr) * QKV_N + kcg * 8;
    const int kldso = sr * 64 + (lane & 7) * 8;   // = ww*512 + lane*8
    // V staging: lane -> row vr = ww*16 + (lane>>2), slot lane&3, chunk slot^f(vr)
    const int vr = ww * 16 + (lane >> 2);
    const int fv = (vr + (vr >> 2)) & 3;
    const int vcg = (lane & 3) ^ fv;
    const __hip_bfloat16* gV = Vbase + (size_t)vr * S_ + khid * 1024 + vcg * 8;
    const int vldso = vr * 32 + (lane & 3) * 8;   // = ww*512 + lane*8

    auto stage = [&](int bf, int it) {
        ASYNC16(gK + (size_t)(it * KT) * QKV_N, &lds_k[(bf * 2 + khid) * 2048 + kldso]);
        ASYNC16(gV + it * KT,                   &lds_v[(bf * 2 + khid) * 2048 + vldso]);
    };

    floatx4 o_acc[2][4];
    floatx4 l_acc[2];
#pragma unroll
    for (int rt = 0; rt < 2; rt++) {
        l_acc[rt] = (floatx4){0.f, 0.f, 0.f, 0.f};
#pragma unroll
        for (int nb = 0; nb < 4; nb++) o_acc[rt][nb] = (floatx4){0.f, 0.f, 0.f, 0.f};
    }
    short8 ones;
#pragma unroll
    for (int i = 0; i < 8; i++) ones[i] = (short)0x3F80;

    __hip_bfloat16* Pw = &lds_p[wave * 1280];

    short8 a_q[2][2];
    auto compute = [&](int bf) {
        const __hip_bfloat16* Kt = &lds_k[(bf * 2 + khid) * 2048];
        const __hip_bfloat16* Vt = &lds_v[(bf * 2 + khid) * 2048];
        short8 bk[2][2];
#pragma unroll
        for (int ct = 0; ct < 2; ct++)
#pragma unroll
            for (int kh = 0; kh < 2; kh++)
                bk[ct][kh] = *(const short8*)&Kt[(ct * 16 + r) * 64 + ((kh * 4 + q) ^ (r & 7)) * 8];
#pragma unroll
        for (int rt = 0; rt < 2; rt++) {
            floatx4 sc[2];
#pragma unroll
            for (int ct = 0; ct < 2; ct++) {
                floatx4 z = (floatx4){0.f, 0.f, 0.f, 0.f};
                z = __builtin_amdgcn_mfma_f32_16x16x32_bf16(a_q[rt][0], bk[ct][0], z, 0, 0, 0);
                z = __builtin_amdgcn_mfma_f32_16x16x32_bf16(a_q[rt][1], bk[ct][1], z, 0, 0, 0);
                sc[ct] = z;
            }
            // score col c = ct*16+r stored at k~ = 2r+ct  (matches per-32 V perm)
#pragma unroll
            for (int reg = 0; reg < 4; reg++) {
                float e0 = EXP2F(fmaf(sc[0][reg], SCALE2, -FM2));
                float e1 = EXP2F(fmaf(sc[1][reg], SCALE2, -FM2));
                *(uint*)&Pw[(rt * 16 + q * 4 + reg) * PPAD + 2 * r] = pack_bf16_2(e0, e1);
            }
        }
        __builtin_amdgcn_s_waitcnt(0xc07f);  // lgkmcnt(0): P visible wave-wide

#pragma unroll
        for (int rt = 0; rt < 2; rt++) {
            short8 pa = *(const short8*)&Pw[(rt * 16 + r) * PPAD + q * 8];
            l_acc[rt] = __builtin_amdgcn_mfma_f32_16x16x32_bf16(pa, ones, l_acc[rt], 0, 0, 0);
#pragma unroll
            for (int nb = 0; nb < 4; nb++) {
                int d = nb * 16 + r;
                short8 vb = *(const short8*)&Vt[d * 32 + ((q ^ ((d + (d >> 2)) & 3)) * 8)];
                o_acc[rt][nb] = __builtin_amdgcn_mfma_f32_16x16x32_bf16(pa, vb, o_acc[rt][nb], 0, 0, 0);
            }
        }
    };

    // prologue: stage(0) + Q loads, drain, stage(1) in flight
    stage(0, 0);
#pragma unroll
    for (int rt = 0; rt < 2; rt++)
#pragma unroll
        for (int kh = 0; kh < 2; kh++)
            a_q[rt][kh] = load8(Qbase + (size_t)(s0 + rt * 16 + r) * QKV_N + kh * 32 + q * 8);
    __builtin_amdgcn_s_waitcnt(0x0F70);
    stage(1, 1);

    for (int it = 0; it < 31; it++) {
        __builtin_amdgcn_s_waitcnt(0x0F72);  // vmcnt(2): buffer it staged (own wave)
        RAW_BARRIER();
        if (it + 2 < 32) stage((it + 2) % 3, it + 2);
        compute(it % 3);
    }
    __builtin_amdgcn_s_waitcnt(0x0F70);      // vmcnt(0): last buffer
    RAW_BARRIER();
    compute(31 % 3);

    // combine k-halves (o,l additive). Reuse K/V LDS (post-barrier).
    __syncthreads();
    float* of = (float*)smem;             // 4 groups x 8KB = 32KB
    float* lf = (float*)(smem + 32768);   // 4 groups x 2KB = 8KB
    if (khid == 1) {
#pragma unroll
        for (int rt = 0; rt < 2; rt++) {
#pragma unroll
            for (int nb = 0; nb < 4; nb++)
                *(floatx4*)&of[ww * 2048 + (rt * 4 + nb) * 256 + lane * 4] = o_acc[rt][nb];
            *(floatx4*)&lf[ww * 512 + rt * 256 + lane * 4] = l_acc[rt];
        }
    }
    __syncthreads();
    if (khid == 0) {
#pragma unroll
        for (int rt = 0; rt < 2; rt++) {
            l_acc[rt] += *(const floatx4*)&lf[ww * 512 + rt * 256 + lane * 4];
#pragma unroll
            for (int nb = 0; nb < 4; nb++)
                o_acc[rt][nb] += *(const floatx4*)&of[ww * 2048 + (rt * 4 + nb) * 256 + lane * 4];
        }
#pragma unroll
        for (int rt = 0; rt < 2; rt++) {
#pragma unroll
            for (int reg = 0; reg < 4; reg++) {
                float inv = 1.f / l_acc[rt][reg];
                int srow2 = s0 + rt * 16 + q * 4 + reg;
                __hip_bfloat16* Orow = O + ((size_t)b * S_ + srow2) * HID + h * DH;
#pragma unroll
                for (int nb = 0; nb < 4; nb++)
                    Orow[nb * 16 + r] = __float2bfloat16(o_acc[rt][nb][reg] * inv);
            }
        }
    }
}

extern "C" void kernel_launch(void* const* d_in, const int* in_sizes, int n_in,
                              void* d_out, int out_size, void* d_ws, size_t ws_size,
                              hipStream_t stream) {
    const float* x_f     = (const float*)d_in[0];
    const float* w_qkv_f = (const float*)d_in[1];
    const float* w_out_f = (const float*)d_in[2];
    const float* b_out_f = (const float*)d_in[3];
    float* out = (float*)d_out;

    __hip_bfloat16* xb      = (__hip_bfloat16*)d_ws;
    __hip_bfloat16* wqkvb   = xb    + (size_t)M_ROWS * HID;
    __hip_bfloat16* woutb   = wqkvb + (size_t)QKV_N * HID;
    __hip_bfloat16* qkv_ws  = woutb + (size_t)HID * HID;
    __hip_bfloat16* vt_ws   = qkv_ws + (size_t)M_ROWS * QKV_N;
    __hip_bfloat16* attn_ws = vt_ws + (size_t)B_ * HID * S_;

    dim3 blk(256);
    {
        int ntot = M_ROWS * HID + QKV_N * HID + HID * HID;
        cvt_all<<<dim3(ntot / 1024), blk, 0, stream>>>(x_f, w_qkv_f, w_out_f, xb);
    }

    gemm_bt_kernel<1, 128><<<dim3(QKV_N / 128, M_ROWS / 128), blk, 0, stream>>>(
        xb, wqkvb, nullptr, qkv_ws, nullptr, vt_ws, M_ROWS, QKV_N, HID);
    flash_kernel<<<dim3(B_ * NH, S_ / 128), dim3(512), 0, stream>>>(qkv_ws, vt_ws, attn_ws);
    gemm_bt_kernel<2, 64><<<dim3(HID / 128, M_ROWS / 64), blk, 0, stream>>>(
        attn_ws, woutb, b_out_f, nullptr, out, nullptr, M_ROWS, HID, HID);
}

// Round 13
// 180.353 us; speedup vs baseline: 1.2422x; 1.0363x over previous
//
#include <hip/hip_runtime.h>
#include <hip/hip_bf16.h>

#define B_ 2
#define S_ 2048
#define HID 1024
#define NH 16
#define DH 64
#define QKV_N (3*HID)
#define M_ROWS (B_*S_)

typedef __attribute__((ext_vector_type(8))) short short8;
typedef __attribute__((ext_vector_type(4))) short short4v;
typedef __attribute__((ext_vector_type(4))) float floatx4;
typedef unsigned int uint;

#define QSCALE 0.18033688f   // 0.125 * log2(e), folded into Q at GEMM1 epilogue

__device__ __forceinline__ short8 load8(const __hip_bfloat16* p) {
    return *(const short8*)p;
}

#if __has_builtin(__builtin_amdgcn_exp2f)
#define EXP2F(x) __builtin_amdgcn_exp2f(x)
#else
#define EXP2F(x) exp2f(x)
#endif

__device__ __forceinline__ uint pack_bf16_2(float lo, float hi) {
    uint ul = __float_as_uint(lo) + 0x8000u;
    uint uh = __float_as_uint(hi) + 0x8000u;
    return __builtin_amdgcn_perm(uh, ul, 0x07060302);
}
__device__ __forceinline__ uint pack_bf16_2_rtne(float lo, float hi) {
    uint ul = __float_as_uint(lo); ul += 0x7FFFu + ((ul >> 16) & 1u);
    uint uh = __float_as_uint(hi); uh += 0x7FFFu + ((uh >> 16) & 1u);
    return __builtin_amdgcn_perm(uh, ul, 0x07060302);
}

#define ASYNC16(gptr, lptr) \
    __builtin_amdgcn_global_load_lds((const __attribute__((address_space(1))) void*)(gptr), \
                                     (__attribute__((address_space(3))) void*)(lptr), 16, 0, 0)
#define RAW_BARRIER() asm volatile("s_barrier" ::: "memory")

// merged f32->bf16 conversion over x | w_qkv | w_out (outputs contiguous)
__global__ __launch_bounds__(256) void cvt_all(
    const float* __restrict__ x, const float* __restrict__ wq,
    const float* __restrict__ wo, __hip_bfloat16* __restrict__ out)
{
    const int n0 = M_ROWS * HID, n1 = QKV_N * HID;
    int i = (blockIdx.x * 256 + threadIdx.x) * 4;
    const float* src; int off;
    if (i < n0)           { src = x;  off = i; }
    else if (i < n0 + n1) { src = wq; off = i - n0; }
    else                  { src = wo; off = i - n0 - n1; }
    float4 v = *(const float4*)(src + off);
    uint2 r;
    r.x = pack_bf16_2_rtne(v.x, v.y);
    r.y = pack_bf16_2_rtne(v.z, v.w);
    *(uint2*)(out + i) = r;
}

// C = A * B^T, K=1024. TMB x 128 tile, BK=32, 3-stage pipeline (raw s_barrier +
// vmcnt(G), prefetch depth 2 — never drains), unrolled x3 so buffer indices and
// LDS addresses are compile-time constant. SWAPPED MFMA operands.
// MODE 1: qkv (bf16): n<1024 (Q) scaled by QSCALE; n<2048 -> C b64 stores;
//         n>=2048 (V) -> VT per-32-permuted, scalar stores.
// MODE 2: bias add, dwordx4 f32 stores.
#define BK 32
#define NITER 32
template<int MODE, int TMB>
__global__ __launch_bounds__(256, (TMB == 128) ? 3 : 4) void gemm_bt_kernel(
    const __hip_bfloat16* __restrict__ A,
    const __hip_bfloat16* __restrict__ Bw,
    const float* __restrict__ biasf,
    __hip_bfloat16* __restrict__ C,
    float* __restrict__ Cf,
    __hip_bfloat16* __restrict__ VT,
    int Mdim, int Ndim, int Kdim)
{
    constexpr int NI = TMB / 32;
    constexpr int CA = TMB / 64;
    constexpr int WAITG = 0x0F70 | (CA + 2);
    __shared__ alignas(16) __hip_bfloat16 As[3][TMB * BK];
    __shared__ alignas(16) __hip_bfloat16 Bs[3][128 * BK];

    const int tid  = threadIdx.x;
    const int wave = tid >> 6;
    const int lane = tid & 63;
    const int q = lane >> 4;
    const int r = lane & 15;
    const int m_blk = blockIdx.y * TMB;
    const int n_blk = blockIdx.x * 128;
    const int wm = (wave >> 1) * (TMB / 2);
    const int wn = (wave & 1) * 64;

    const __hip_bfloat16* Abase = A + (size_t)m_blk * Kdim;
    const __hip_bfloat16* Bbase = Bw + (size_t)n_blk * Kdim;

    floatx4 acc[NI][4];
#pragma unroll
    for (int i = 0; i < NI; i++)
#pragma unroll
        for (int j = 0; j < 4; j++) acc[i][j] = (floatx4){0.f, 0.f, 0.f, 0.f};

    auto stage = [&](int bf, int kt) {
#pragma unroll
        for (int c = 0; c < CA; c++) {
            int ch = tid + c * 256;
            ASYNC16(Abase + (size_t)(ch >> 2) * Kdim + kt + (ch & 3) * 8, &As[bf][ch * 8]);
        }
#pragma unroll
        for (int c = 0; c < 2; c++) {
            int ch = tid + c * 256;
            ASYNC16(Bbase + (size_t)(ch >> 2) * Kdim + kt + (ch & 3) * 8, &Bs[bf][ch * 8]);
        }
    };
    auto compute = [&](int bf) {
        short8 a[NI], b[4];
#pragma unroll
        for (int i = 0; i < NI; i++) a[i] = *(const short8*)&As[bf][(wm + i * 16 + r) * BK + q * 8];
#pragma unroll
        for (int j = 0; j < 4; j++) b[j] = *(const short8*)&Bs[bf][(wn + j * 16 + r) * BK + q * 8];
#pragma unroll
        for (int i = 0; i < NI; i++)
#pragma unroll
            for (int j = 0; j < 4; j++)   // SWAPPED: first operand = B -> acc[m=..+r][n=..+q*4+reg]
                acc[i][j] = __builtin_amdgcn_mfma_f32_16x16x32_bf16(b[j], a[i], acc[i][j], 0, 0, 0);
    };

    stage(0, 0);
    stage(1, BK);
#pragma unroll 3
    for (int it = 0; it < NITER - 2; it++) {
        __builtin_amdgcn_s_waitcnt(WAITG);
        RAW_BARRIER();
        stage((it + 2) % 3, (it + 2) * BK);
        compute(it % 3);
    }
    __builtin_amdgcn_s_waitcnt(WAITG);
    RAW_BARRIER();
    compute((NITER - 2) % 3);
    __builtin_amdgcn_s_waitcnt(0x0F70);
    RAW_BARRIER();
    compute((NITER - 1) % 3);

    // epilogue (swapped layout): m = m_blk+wm+i*16+r, n = n_blk+wn+j*16+q*4+reg
#pragma unroll
    for (int i = 0; i < NI; i++) {
        const int m = m_blk + wm + i * 16 + r;
#pragma unroll
        for (int j = 0; j < 4; j++) {
            const int n0 = n_blk + wn + j * 16 + q * 4;
            if (MODE == 2) {
                float4 bv = *(const float4*)&biasf[n0];
                float4 ov;
                ov.x = acc[i][j][0] + bv.x;
                ov.y = acc[i][j][1] + bv.y;
                ov.z = acc[i][j][2] + bv.z;
                ov.w = acc[i][j][3] + bv.w;
                *(float4*)&Cf[(size_t)m * Ndim + n0] = ov;
            } else if (n_blk < 2 * HID) {
                // Q region (n < 1024): fold softmax scale into Q
                float s = (n0 < HID) ? QSCALE : 1.0f;
                uint2 pk;
                pk.x = pack_bf16_2_rtne(acc[i][j][0] * s, acc[i][j][1] * s);
                pk.y = pack_bf16_2_rtne(acc[i][j][2] * s, acc[i][j][3] * s);
                *(uint2*)&C[(size_t)m * QKV_N + n0] = pk;
            } else {
                // V: per-32 permuted transpose store (scalar)
                int bidx = m >> 11;
                int srow = m & (S_ - 1);
                int c = srow & 31;
                int sp = (srow & ~31) | ((c & 15) << 1) | ((c >> 4) & 1);
#pragma unroll
                for (int reg = 0; reg < 4; reg++) {
                    int dfull = n0 + reg - 2 * HID;
                    VT[((size_t)bidx * HID + dfull) * S_ + sp] =
                        __float2bfloat16(acc[i][j][reg]);
                }
            }
        }
    }
}

// Flash attention v11: v10 structure (512 thr = 4 q-groups x 2 k-halves, KT=32,
// 3-stage pipeline) with: Q pre-scaled -> P = exp2(sc) directly (no fma, no FM2;
// unnormalized P cancels in o/l), and the pipeline loop unrolled x3 so buffer
// indices/LDS addresses are compile-time constants.
#define KT 32
#define PPAD 40

__global__ __launch_bounds__(512, 4) void flash_kernel(
    const __hip_bfloat16* __restrict__ qkv,  // [B][S][3072], Q pre-scaled
    const __hip_bfloat16* __restrict__ VTp,  // [B][HID][S'] per-32 permuted
    __hip_bfloat16* __restrict__ O)          // [B][S][1024]
{
    __shared__ alignas(16) char smem[69632];
    __hip_bfloat16* lds_k = (__hip_bfloat16*)smem;            // [3][2][2048] 24KB
    __hip_bfloat16* lds_v = (__hip_bfloat16*)(smem + 24576);  // [3][2][2048] 24KB
    __hip_bfloat16* lds_p = (__hip_bfloat16*)(smem + 49152);  // [8][1280]    20KB

    const int tid  = threadIdx.x;
    const int wave = tid >> 6;
    const int lane = tid & 63;
    const int q = lane >> 4;
    const int r = lane & 15;
    const int ww   = wave & 3;    // q-group
    const int khid = wave >> 2;   // k-half
    const int bh = blockIdx.x;
    const int b  = bh >> 4;
    const int h  = bh & 15;
    const int s0 = blockIdx.y * 128 + ww * 32;

    const __hip_bfloat16* Qbase = qkv + (size_t)b * S_ * QKV_N + h * DH;
    const __hip_bfloat16* Kbase = Qbase + HID;
    const __hip_bfloat16* Vbase = VTp + ((size_t)b * HID + h * DH) * S_;

    // K staging: lane -> row sr = ww*8 + (lane>>3), slot lane&7, chunk slot^(sr&7)
    const int sr = ww * 8 + (lane >> 3);
    const int kcg = (lane & 7) ^ ((lane >> 3) & 7);
    const __hip_bfloat16* gK = Kbase + (size_t)(khid * 1024 + sr) * QKV_N + kcg * 8;
    const int kldso = sr * 64 + (lane & 7) * 8;
    // V staging: lane -> row vr = ww*16 + (lane>>2), slot lane&3, chunk slot^f(vr)
    const int vr = ww * 16 + (lane >> 2);
    const int fv = (vr + (vr >> 2)) & 3;
    const int vcg = (lane & 3) ^ fv;
    const __hip_bfloat16* gV = Vbase + (size_t)vr * S_ + khid * 1024 + vcg * 8;
    const int vldso = vr * 32 + (lane & 3) * 8;

    auto stage = [&](int bf, int it) {
        ASYNC16(gK + (size_t)(it * KT) * QKV_N, &lds_k[(bf * 2 + khid) * 2048 + kldso]);
        ASYNC16(gV + it * KT,                   &lds_v[(bf * 2 + khid) * 2048 + vldso]);
    };

    floatx4 o_acc[2][4];
    floatx4 l_acc[2];
#pragma unroll
    for (int rt = 0; rt < 2; rt++) {
        l_acc[rt] = (floatx4){0.f, 0.f, 0.f, 0.f};
#pragma unroll
        for (int nb = 0; nb < 4; nb++) o_acc[rt][nb] = (floatx4){0.f, 0.f, 0.f, 0.f};
    }
    short8 ones;
#pragma unroll
    for (int i = 0; i < 8; i++) ones[i] = (short)0x3F80;

    __hip_bfloat16* Pw = &lds_p[wave * 1280];

    short8 a_q[2][2];
    auto compute = [&](int bf) {
        const __hip_bfloat16* Kt = &lds_k[(bf * 2 + khid) * 2048];
        const __hip_bfloat16* Vt = &lds_v[(bf * 2 + khid) * 2048];
        short8 bk[2][2];
#pragma unroll
        for (int ct = 0; ct < 2; ct++)
#pragma unroll
            for (int kh = 0; kh < 2; kh++)
                bk[ct][kh] = *(const short8*)&Kt[(ct * 16 + r) * 64 + ((kh * 4 + q) ^ (r & 7)) * 8];
#pragma unroll
        for (int rt = 0; rt < 2; rt++) {
            floatx4 sc[2];
#pragma unroll
            for (int ct = 0; ct < 2; ct++) {
                floatx4 z = (floatx4){0.f, 0.f, 0.f, 0.f};
                z = __builtin_amdgcn_mfma_f32_16x16x32_bf16(a_q[rt][0], bk[ct][0], z, 0, 0, 0);
                z = __builtin_amdgcn_mfma_f32_16x16x32_bf16(a_q[rt][1], bk[ct][1], z, 0, 0, 0);
                sc[ct] = z;
            }
            // Q pre-scaled: P = exp2(sc), unnormalized (cancels in o/l).
            // score col c = ct*16+r stored at k~ = 2r+ct (matches per-32 V perm)
#pragma unroll
            for (int reg = 0; reg < 4; reg++) {
                float e0 = EXP2F(sc[0][reg]);
                float e1 = EXP2F(sc[1][reg]);
                *(uint*)&Pw[(rt * 16 + q * 4 + reg) * PPAD + 2 * r] = pack_bf16_2(e0, e1);
            }
        }
        __builtin_amdgcn_s_waitcnt(0xc07f);  // lgkmcnt(0): P visible wave-wide

#pragma unroll
        for (int rt = 0; rt < 2; rt++) {
            short8 pa = *(const short8*)&Pw[(rt * 16 + r) * PPAD + q * 8];
            l_acc[rt] = __builtin_amdgcn_mfma_f32_16x16x32_bf16(pa, ones, l_acc[rt], 0, 0, 0);
#pragma unroll
            for (int nb = 0; nb < 4; nb++) {
                int d = nb * 16 + r;
                short8 vb = *(const short8*)&Vt[d * 32 + ((q ^ ((d + (d >> 2)) & 3)) * 8)];
                o_acc[rt][nb] = __builtin_amdgcn_mfma_f32_16x16x32_bf16(pa, vb, o_acc[rt][nb], 0, 0, 0);
            }
        }
    };

    // one pipelined step; bf passed as a constant at each call site
    auto step = [&](int it, int bf) {
        __builtin_amdgcn_s_waitcnt(0x0F72);  // vmcnt(2): buffer `it` staged (own wave)
        RAW_BARRIER();
        stage((bf + 2) % 3, it + 2);
        compute(bf);
    };

    // prologue: stage(0) + Q loads, drain, stage(1) in flight
    stage(0, 0);
#pragma unroll
    for (int rt = 0; rt < 2; rt++)
#pragma unroll
        for (int kh = 0; kh < 2; kh++)
            a_q[rt][kh] = load8(Qbase + (size_t)(s0 + rt * 16 + r) * QKV_N + kh * 32 + q * 8);
    __builtin_amdgcn_s_waitcnt(0x0F70);
    stage(1, 1);

    for (int itb = 0; itb < 30; itb += 3) {   // x3 unroll: bf compile-time constant
        step(itb + 0, 0);
        step(itb + 1, 1);
        step(itb + 2, 2);
    }
    __builtin_amdgcn_s_waitcnt(0x0F72);      // it=30
    RAW_BARRIER();
    compute(0);
    __builtin_amdgcn_s_waitcnt(0x0F70);      // it=31: last buffer
    RAW_BARRIER();
    compute(1);

    // combine k-halves (o,l additive). Reuse K/V LDS (post-barrier).
    __syncthreads();
    float* of = (float*)smem;             // 4 groups x 8KB = 32KB
    float* lf = (float*)(smem + 32768);   // 4 groups x 2KB = 8KB
    if (khid == 1) {
#pragma unroll
        for (int rt = 0; rt < 2; rt++) {
#pragma unroll
            for (int nb = 0; nb < 4; nb++)
                *(floatx4*)&of[ww * 2048 + (rt * 4 + nb) * 256 + lane * 4] = o_acc[rt][nb];
            *(floatx4*)&lf[ww * 512 + rt * 256 + lane * 4] = l_acc[rt];
        }
    }
    __syncthreads();
    if (khid == 0) {
#pragma unroll
        for (int rt = 0; rt < 2; rt++) {
            l_acc[rt] += *(const floatx4*)&lf[ww * 512 + rt * 256 + lane * 4];
#pragma unroll
            for (int nb = 0; nb < 4; nb++)
                o_acc[rt][nb] += *(const floatx4*)&of[ww * 2048 + (rt * 4 + nb) * 256 + lane * 4];
        }
#pragma unroll
        for (int rt = 0; rt < 2; rt++) {
#pragma unroll
            for (int reg = 0; reg < 4; reg++) {
                float inv = 1.f / l_acc[rt][reg];
                int srow2 = s0 + rt * 16 + q * 4 + reg;
                __hip_bfloat16* Orow = O + ((size_t)b * S_ + srow2) * HID + h * DH;
#pragma unroll
                for (int nb = 0; nb < 4; nb++)
                    Orow[nb * 16 + r] = __float2bfloat16(o_acc[rt][nb][reg] * inv);
            }
        }
    }
}

extern "C" void kernel_launch(void* const* d_in, const int* in_sizes, int n_in,
                              void* d_out, int out_size, void* d_ws, size_t ws_size,
                              hipStream_t stream) {
    const float* x_f     = (const float*)d_in[0];
    const float* w_qkv_f = (const float*)d_in[1];
    const float* w_out_f = (const float*)d_in[2];
    const float* b_out_f = (const float*)d_in[3];
    float* out = (float*)d_out;

    __hip_bfloat16* xb      = (__hip_bfloat16*)d_ws;
    __hip_bfloat16* wqkvb   = xb    + (size_t)M_ROWS * HID;
    __hip_bfloat16* woutb   = wqkvb + (size_t)QKV_N * HID;
    __hip_bfloat16* qkv_ws  = woutb + (size_t)HID * HID;
    __hip_bfloat16* vt_ws   = qkv_ws + (size_t)M_ROWS * QKV_N;
    __hip_bfloat16* attn_ws = vt_ws + (size_t)B_ * HID * S_;

    dim3 blk(256);
    {
        int ntot = M_ROWS * HID + QKV_N * HID + HID * HID;
        cvt_all<<<dim3(ntot / 1024), blk, 0, stream>>>(x_f, w_qkv_f, w_out_f, xb);
    }

    gemm_bt_kernel<1, 128><<<dim3(QKV_N / 128, M_ROWS / 128), blk, 0, stream>>>(
        xb, wqkvb, nullptr, qkv_ws, nullptr, vt_ws, M_ROWS, QKV_N, HID);
    flash_kernel<<<dim3(B_ * NH, S_ / 128), dim3(512), 0, stream>>>(qkv_ws, vt_ws, attn_ws);
    gemm_bt_kernel<2, 64><<<dim3(HID / 128, M_ROWS / 64), blk, 0, stream>>>(
        attn_ws, woutb, b_out_f, nullptr, out, nullptr, M_ROWS, HID, HID);
}